// Round 5
// baseline (209.917 us; speedup 1.0000x reference)
//
#include <hip/hip_runtime.h>

typedef __bf16 bf16x8 __attribute__((ext_vector_type(8)));
typedef float f32x4 __attribute__((ext_vector_type(4)));
typedef float f32x16 __attribute__((ext_vector_type(16)));
typedef unsigned short ushort8 __attribute__((ext_vector_type(8)));
typedef unsigned int uint4v __attribute__((ext_vector_type(4)));

__device__ __forceinline__ unsigned short f2bf(float f) {
  __bf16 b = (__bf16)f;
  return __builtin_bit_cast(unsigned short, b);
}
__device__ __forceinline__ float bf2f(unsigned short u) {
  unsigned int x = ((unsigned int)u) << 16;
  return __builtin_bit_cast(float, x);
}

// async global->LDS, 16B per lane; LDS dest must be wave-uniform base + lane*16
#define GLOAD_LDS16(g, l)                                              \
  __builtin_amdgcn_global_load_lds(                                    \
      (const __attribute__((address_space(1))) void*)(g),              \
      (__attribute__((address_space(3))) void*)(l), 16, 0, 0)

// ---------------- x f32 -> bf16 ----------------
__global__ __launch_bounds__(256) void f32_to_bf16_kernel(const float* __restrict__ in,
                                                          __bf16* __restrict__ out) {
  int i = blockIdx.x * 256 + threadIdx.x;
  const float4* p = (const float4*)(in + (size_t)i * 8);
  float4 f0 = p[0], f1 = p[1];
  ushort8 u = {f2bf(f0.x), f2bf(f0.y), f2bf(f0.z), f2bf(f0.w),
               f2bf(f1.x), f2bf(f1.y), f2bf(f1.z), f2bf(f1.w)};
  *(ushort8*)((unsigned short*)out + (size_t)i * 8) = u;
}

// ---------------- W transpose + f32->bf16 convert: Wt[n][k] = W[k][n] ----------------
__global__ __launch_bounds__(256) void wtrans_kernel(const float* __restrict__ W,
                                                     __bf16* __restrict__ Wt,
                                                     int K, int N) {
  __shared__ float tile[32][33];
  int tx = threadIdx.x, ty = threadIdx.y;  // block (32,8)
  int n0 = blockIdx.x * 32, k0 = blockIdx.y * 32;
#pragma unroll
  for (int i = 0; i < 32; i += 8)
    tile[ty + i][tx] = W[(size_t)(k0 + ty + i) * N + n0 + tx];
  __syncthreads();
#pragma unroll
  for (int i = 0; i < 32; i += 8)
    Wt[(size_t)(n0 + ty + i) * K + k0 + tx] = (__bf16)tile[tx][ty + i];
}

// ---------------- GEMM: C[M,N] = A[M,K] @ Bt[N,K]^T + bias (m97 structure) ----------------
template <int OUT_F32>
__global__ __launch_bounds__(256) void gemm_bt_kernel(const __bf16* __restrict__ Ab,
                                                      const __bf16* __restrict__ Bt,
                                                      const float* __restrict__ bias,
                                                      void* __restrict__ Cp,
                                                      int M, int N, int K) {
  __shared__ __align__(16) unsigned short As[128 * 32];
  __shared__ __align__(16) unsigned short Bs[128 * 32];
  const int tid = threadIdx.x;
  const int lane = tid & 63;
  const int wid = tid >> 6;
  const int lr = lane & 15, lg = lane >> 4;
  const int gx = gridDim.x;
  int nwg = gx * gridDim.y;
  int bid = blockIdx.y * gx + blockIdx.x;
  if ((nwg & 7) == 0) {
    int cpx = nwg >> 3;
    bid = (bid & 7) * cpx + (bid >> 3);
  }
  const int m0 = (bid / gx) * 128, n0 = (bid % gx) * 128;
  const int wm = (wid >> 1) * 64, wn = (wid & 1) * 64;
  const int sr = tid >> 2, sc = (tid & 3) * 8;
  const unsigned short* Ag = (const unsigned short*)Ab + (size_t)(m0 + sr) * K + sc;
  const unsigned short* Bg = (const unsigned short*)Bt + (size_t)(n0 + sr) * K + sc;
  f32x4 acc[4][4] = {};
  for (int k0 = 0; k0 < K; k0 += 32) {
    GLOAD_LDS16(Ag + k0, As + tid * 8);
    GLOAD_LDS16(Ag + (size_t)64 * K + k0, As + 2048 + tid * 8);
    GLOAD_LDS16(Bg + k0, Bs + tid * 8);
    GLOAD_LDS16(Bg + (size_t)64 * K + k0, Bs + 2048 + tid * 8);
    __syncthreads();
    bf16x8 af[4], bfr[4];
#pragma unroll
    for (int i = 0; i < 4; ++i) af[i] = *(const bf16x8*)&As[(wm + i * 16 + lr) * 32 + lg * 8];
#pragma unroll
    for (int i = 0; i < 4; ++i) bfr[i] = *(const bf16x8*)&Bs[(wn + i * 16 + lr) * 32 + lg * 8];
#pragma unroll
    for (int i = 0; i < 4; ++i)
#pragma unroll
      for (int jn = 0; jn < 4; ++jn)
        acc[i][jn] = __builtin_amdgcn_mfma_f32_16x16x32_bf16(af[i], bfr[jn], acc[i][jn], 0, 0, 0);
    __syncthreads();
  }
#pragma unroll
  for (int i = 0; i < 4; ++i)
#pragma unroll
    for (int jn = 0; jn < 4; ++jn)
#pragma unroll
      for (int jj = 0; jj < 4; ++jj) {
        int row = m0 + wm + i * 16 + lg * 4 + jj;
        int col = n0 + wn + jn * 16 + lr;
        float v = acc[i][jn][jj] + bias[col];
        if (OUT_F32)
          ((float*)Cp)[(size_t)row * N + col] = v;
        else
          ((unsigned short*)Cp)[(size_t)row * N + col] = f2bf(v);
      }
}

// ---------------- qkv(k part) -> Kb [B,H,T,D] ----------------
__global__ __launch_bounds__(256) void reshape_k_kernel(const __bf16* __restrict__ qkv,
                                                        __bf16* __restrict__ Ko) {
  int tid = blockIdx.x * 256 + threadIdx.x;
  int d8 = tid & 7;
  int t = (tid >> 3) & 2047;
  int h = (tid >> 14) & 15;
  int b = tid >> 18;
  size_t src = (size_t)(b * 2048 + t) * 3072 + 1024 + h * 64 + d8 * 8;
  size_t dst = (size_t)((b * 16 + h) * 2048 + t) * 64 + d8 * 8;
  *(ushort8*)((unsigned short*)Ko + dst) = *(const ushort8*)((const unsigned short*)qkv + src);
}

// ---------------- qkv(v part) -> Vt [B,H,D,T] (tiled transpose) ----------------
__global__ __launch_bounds__(256) void vtrans_kernel(const __bf16* __restrict__ qkv,
                                                     __bf16* __restrict__ Vt) {
  __shared__ __align__(16) unsigned short tile[64][72];
  int bh = blockIdx.y, b = bh >> 4, h = bh & 15;
  int t0 = blockIdx.x * 64;
  int tid = threadIdx.x;
#pragma unroll
  for (int p = 0; p < 2; ++p) {
    int idx = p * 256 + tid;
    int r = idx >> 3, c8 = (idx & 7) * 8;
    *(ushort8*)&tile[r][c8] = *(const ushort8*)((const unsigned short*)qkv +
                                                (size_t)(b * 2048 + t0 + r) * 3072 + 2048 +
                                                h * 64 + c8);
  }
  __syncthreads();
#pragma unroll
  for (int p = 0; p < 2; ++p) {
    int idx = p * 256 + tid;
    int d = idx >> 3, c8 = (idx & 7) * 8;
    ushort8 u;
#pragma unroll
    for (int i = 0; i < 8; ++i) u[i] = tile[c8 + i][d];
    *(ushort8*)((unsigned short*)Vt + (size_t)(bh * 64 + d) * 2048 + t0 + c8) = u;
  }
}

// ---------------- flash attention (causal), swapped-QK^T 32x32 ----------------
// Round-3 staging flow (immediate load->LDS before compute; compiler overlaps)
// + round-4 VALU cuts (pre-scaled Q, diag-only mask, pair-tree max, defer-max).
__global__ __launch_bounds__(256) void attn_kernel(const __bf16* __restrict__ qkvp,
                                                   const __bf16* __restrict__ Kg,
                                                   const __bf16* __restrict__ Vt,
                                                   __bf16* __restrict__ yb) {
  __shared__ __align__(16) unsigned short Ks[2][64][72];
  __shared__ __align__(16) unsigned short Vs[2][64][72];
  const int bx = blockIdx.x;
  const int qb = 15 - (bx >> 6);  // heavy blocks first
  const int bh = bx & 63;
  const int b = bh >> 4, h = bh & 15;
  const int tid = threadIdx.x, wid = tid >> 6, lane = tid & 63;
  const int lq = lane & 31, hi = lane >> 5;
  const unsigned short* qkv = (const unsigned short*)qkvp;
  const unsigned short* Kh = (const unsigned short*)Kg + (size_t)bh * 2048 * 64;
  const unsigned short* Vh = (const unsigned short*)Vt + (size_t)bh * 64 * 2048;
  const int q0w = qb * 128 + wid * 32;
  const int jmax_w = 2 * qb + (wid >> 1);
  const int qrel = (wid & 1) * 32 + lq;
  const int J = 2 * qb + 2;

  // Q B-fragments, pre-scaled by 1/sqrt(d)*log2(e), read once from qkv
  const float qs = 0.125f * 1.44269504f;
  bf16x8 qf[4];
  {
    const unsigned short* Qg = qkv + (size_t)(b * 2048 + q0w + lq) * 3072 + h * 64;
#pragma unroll
    for (int dc = 0; dc < 4; ++dc) {
      ushort8 uq = *(const ushort8*)(Qg + dc * 16 + hi * 8);
      uint4v w;
#pragma unroll
      for (int i = 0; i < 4; ++i) {
        float lo = bf2f(uq[2 * i]) * qs;
        float hh = bf2f(uq[2 * i + 1]) * qs;
        unsigned int up;
        asm("v_cvt_pk_bf16_f32 %0, %1, %2" : "=v"(up) : "v"(lo), "v"(hh));
        w[i] = up;
      }
      qf[dc] = __builtin_bit_cast(bf16x8, w);
    }
  }

  f32x16 yacc[2] = {};
  float m_r = -1e30f, l_r = 0.f;

  // prologue: stage tile 0 into buffer 0
  {
#pragma unroll
    for (int p = 0; p < 2; ++p) {
      int idx = p * 256 + tid;
      int r = idx >> 3, c8 = (idx & 7) * 8;
      *(ushort8*)&Ks[0][r][c8] = *(const ushort8*)(Kh + (size_t)r * 64 + c8);
      *(ushort8*)&Vs[0][r][c8] = *(const ushort8*)(Vh + (size_t)r * 2048 + c8);
    }
  }

  for (int j = 0; j < J; ++j) {
    __syncthreads();  // buf (j&1) holds tile j; prior reads of other buf done
    if (j + 1 < J) {  // stage next tile; compiler overlaps loads with compute below
      int bi = (j + 1) & 1;
#pragma unroll
      for (int p = 0; p < 2; ++p) {
        int idx = p * 256 + tid;
        int r = idx >> 3, c8 = (idx & 7) * 8;
        *(ushort8*)&Ks[bi][r][c8] =
            *(const ushort8*)(Kh + (size_t)((j + 1) * 64 + r) * 64 + c8);
        *(ushort8*)&Vs[bi][r][c8] =
            *(const ushort8*)(Vh + (size_t)r * 2048 + (j + 1) * 64 + c8);
      }
    }
    if (j <= jmax_w) {
      const int cb = j & 1;
      // --- S^T = K @ Q^T (Q pre-scaled)
      f32x16 sa[2];
      __builtin_amdgcn_s_setprio(1);
#pragma unroll
      for (int kt32 = 0; kt32 < 2; ++kt32) {
        f32x16 s = {};
#pragma unroll
        for (int dc = 0; dc < 4; ++dc) {
          bf16x8 kf = *(const bf16x8*)&Ks[cb][kt32 * 32 + lq][dc * 16 + hi * 8];
          s = __builtin_amdgcn_mfma_f32_32x32x16_bf16(kf, qf[dc], s, 0, 0, 0);
        }
        sa[kt32] = s;
      }
      __builtin_amdgcn_s_setprio(0);
      // --- causal mask (diagonal tile only, wave-uniform branch)
      if (j == jmax_w) {
#pragma unroll
        for (int kt32 = 0; kt32 < 2; ++kt32)
#pragma unroll
          for (int reg = 0; reg < 16; ++reg) {
            int kl = kt32 * 32 + (reg & 3) + 8 * (reg >> 2) + 4 * hi;
            if (kl > qrel) sa[kt32][reg] = -1e30f;
          }
      }
      // --- row max (pair tree), defer-max
      float pmax = -1e30f;
#pragma unroll
      for (int kt32 = 0; kt32 < 2; ++kt32)
#pragma unroll
        for (int reg = 0; reg < 16; reg += 4)
          pmax = fmaxf(pmax, fmaxf(fmaxf(sa[kt32][reg], sa[kt32][reg + 1]),
                                   fmaxf(sa[kt32][reg + 2], sa[kt32][reg + 3])));
      pmax = fmaxf(pmax, __shfl_xor(pmax, 32));
      const bool need = __any(pmax > m_r + 8.f) != 0;
      const float mnew = need ? fmaxf(m_r, pmax) : m_r;
      const float alpha = exp2f(m_r - mnew);
      // --- exp + row sum + pack to bf16 pairs
      unsigned int u[2][8];
      float rs = 0.f;
#pragma unroll
      for (int kt32 = 0; kt32 < 2; ++kt32)
#pragma unroll
        for (int r = 0; r < 8; ++r) {
          float p0 = exp2f(sa[kt32][2 * r] - mnew);
          float p1 = exp2f(sa[kt32][2 * r + 1] - mnew);
          rs += p0 + p1;
          unsigned int up;
          asm("v_cvt_pk_bf16_f32 %0, %1, %2" : "=v"(up) : "v"(p0), "v"(p1));
          u[kt32][r] = up;
        }
      rs += __shfl_xor(rs, 32);
      l_r = l_r * alpha + rs;
      m_r = mnew;
      if (need) {
#pragma unroll
        for (int reg = 0; reg < 16; ++reg) {
          int row = (reg & 3) + 8 * (reg >> 2) + 4 * hi;
          float ac = __shfl(alpha, row);
          yacc[0][reg] *= ac;
          yacc[1][reg] *= ac;
        }
      }
      // --- PV: repack P via permlane32_swap, accumulate Y
      __builtin_amdgcn_s_setprio(1);
#pragma unroll
      for (int kt = 0; kt < 4; ++kt) {
        const int kt32 = kt >> 1, off = 4 * (kt & 1);
        unsigned int a0 = u[kt32][off + 0], a2 = u[kt32][off + 2];
        unsigned int a1 = u[kt32][off + 1], a3 = u[kt32][off + 3];
        asm("v_permlane32_swap_b32 %0, %1" : "+v"(a0), "+v"(a2));
        asm("v_permlane32_swap_b32 %0, %1" : "+v"(a1), "+v"(a3));
        uint4v pav = {a0, a1, a2, a3};
        bf16x8 paf = __builtin_bit_cast(bf16x8, pav);
#pragma unroll
        for (int dt = 0; dt < 2; ++dt) {
          bf16x8 vf = *(const bf16x8*)&Vs[cb][dt * 32 + lq][kt * 16 + hi * 8];
          yacc[dt] = __builtin_amdgcn_mfma_f32_32x32x16_bf16(paf, vf, yacc[dt], 0, 0, 0);
        }
      }
      __builtin_amdgcn_s_setprio(0);
    }
  }
  // --- epilogue
#pragma unroll
  for (int reg = 0; reg < 16; ++reg) {
    int row = (reg & 3) + 8 * (reg >> 2) + 4 * hi;
    float linv = 1.f / __shfl(l_r, row);
    int qg = q0w + row;
#pragma unroll
    for (int dt = 0; dt < 2; ++dt) {
      float v = yacc[dt][reg] * linv;
      ((unsigned short*)yb)[(size_t)(b * 2048 + qg) * 1024 + h * 64 + dt * 32 + lq] = f2bf(v);
    }
  }
}

extern "C" void kernel_launch(void* const* d_in, const int* in_sizes, int n_in,
                              void* d_out, int out_size, void* d_ws, size_t ws_size,
                              hipStream_t stream) {
  const float* x = (const float*)d_in[0];
  const float* W_attn = (const float*)d_in[1];
  const float* b_attn = (const float*)d_in[2];
  const float* W_proj = (const float*)d_in[3];
  const float* b_proj = (const float*)d_in[4];
  float* out = (float*)d_out;
  char* ws = (char*)d_ws;

  size_t off = 0;
  __bf16* WtA = (__bf16*)(ws + off); off += (size_t)3072 * 1024 * 2;
  __bf16* WtP = (__bf16*)(ws + off); off += (size_t)1024 * 1024 * 2;
  __bf16* qkv = (__bf16*)(ws + off); off += (size_t)8192 * 3072 * 2;
  __bf16* Kb  = (__bf16*)(ws + off); off += (size_t)64 * 2048 * 64 * 2;
  __bf16* Vtb = (__bf16*)(ws + off); off += (size_t)64 * 2048 * 64 * 2;
  // xb (x in bf16) is dead after GEMM1; yb written only after attn -> alias
  __bf16* xyb = (__bf16*)(ws + off); off += (size_t)8192 * 1024 * 2;
  __bf16* xb = xyb;
  __bf16* yb = xyb;
  (void)ws_size; (void)in_sizes; (void)n_in; (void)out_size;

  f32_to_bf16_kernel<<<4096, 256, 0, stream>>>(x, xb);
  wtrans_kernel<<<dim3(3072 / 32, 1024 / 32), dim3(32, 8), 0, stream>>>(W_attn, WtA, 1024, 3072);
  wtrans_kernel<<<dim3(1024 / 32, 1024 / 32), dim3(32, 8), 0, stream>>>(W_proj, WtP, 1024, 1024);
  gemm_bt_kernel<0><<<dim3(24, 64), 256, 0, stream>>>(xb, WtA, b_attn, qkv, 8192, 3072, 1024);
  reshape_k_kernel<<<4096, 256, 0, stream>>>(qkv, Kb);
  vtrans_kernel<<<dim3(32, 64), 256, 0, stream>>>(qkv, Vtb);
  attn_kernel<<<dim3(1024), 256, 0, stream>>>(qkv, Kb, Vtb, yb);
  gemm_bt_kernel<1><<<dim3(8, 64), 256, 0, stream>>>(yb, WtP, b_proj, out, 8192, 1024, 1024);
}

// Round 6
// 201.994 us; speedup vs baseline: 1.0392x; 1.0392x over previous
//
#include <hip/hip_runtime.h>

typedef __bf16 bf16x8 __attribute__((ext_vector_type(8)));
typedef float f32x4 __attribute__((ext_vector_type(4)));
typedef float f32x16 __attribute__((ext_vector_type(16)));
typedef unsigned short ushort8 __attribute__((ext_vector_type(8)));
typedef unsigned int uint4v __attribute__((ext_vector_type(4)));

__device__ __forceinline__ unsigned short f2bf(float f) {
  __bf16 b = (__bf16)f;
  return __builtin_bit_cast(unsigned short, b);
}
__device__ __forceinline__ float bf2f(unsigned short u) {
  unsigned int x = ((unsigned int)u) << 16;
  return __builtin_bit_cast(float, x);
}

// async global->LDS, 16B per lane; LDS dest must be wave-uniform base + lane*16
#define GLOAD_LDS16(g, l)                                              \
  __builtin_amdgcn_global_load_lds(                                    \
      (const __attribute__((address_space(1))) void*)(g),              \
      (__attribute__((address_space(3))) void*)(l), 16, 0, 0)

// ---------------- x f32 -> bf16 ----------------
__global__ __launch_bounds__(256) void f32_to_bf16_kernel(const float* __restrict__ in,
                                                          __bf16* __restrict__ out) {
  int i = blockIdx.x * 256 + threadIdx.x;
  const float4* p = (const float4*)(in + (size_t)i * 8);
  float4 f0 = p[0], f1 = p[1];
  ushort8 u = {f2bf(f0.x), f2bf(f0.y), f2bf(f0.z), f2bf(f0.w),
               f2bf(f1.x), f2bf(f1.y), f2bf(f1.z), f2bf(f1.w)};
  *(ushort8*)((unsigned short*)out + (size_t)i * 8) = u;
}

// ---------------- W transpose + f32->bf16 convert: Wt[n][k] = W[k][n] ----------------
__global__ __launch_bounds__(256) void wtrans_kernel(const float* __restrict__ W,
                                                     __bf16* __restrict__ Wt,
                                                     int K, int N) {
  __shared__ float tile[32][33];
  int tx = threadIdx.x, ty = threadIdx.y;  // block (32,8)
  int n0 = blockIdx.x * 32, k0 = blockIdx.y * 32;
#pragma unroll
  for (int i = 0; i < 32; i += 8)
    tile[ty + i][tx] = W[(size_t)(k0 + ty + i) * N + n0 + tx];
  __syncthreads();
#pragma unroll
  for (int i = 0; i < 32; i += 8)
    Wt[(size_t)(n0 + ty + i) * K + k0 + tx] = (__bf16)tile[tx][ty + i];
}

// ---------------- GEMM: C[M,N] = A[M,K] @ Bt[N,K]^T + bias (m97 structure) ----------------
// KSPLIT=1: blocks whose columns fall in [1024,2048) (the K part of qkv) write
// to Kb[B,H,T,D] instead of Cp (block-uniform redirect; fuses reshape_k).
template <int OUT_F32, int KSPLIT>
__global__ __launch_bounds__(256) void gemm_bt_kernel(const __bf16* __restrict__ Ab,
                                                      const __bf16* __restrict__ Bt,
                                                      const float* __restrict__ bias,
                                                      void* __restrict__ Cp,
                                                      __bf16* __restrict__ Kbp,
                                                      int M, int N, int K) {
  __shared__ __align__(16) unsigned short As[128 * 32];
  __shared__ __align__(16) unsigned short Bs[128 * 32];
  const int tid = threadIdx.x;
  const int lane = tid & 63;
  const int wid = tid >> 6;
  const int lr = lane & 15, lg = lane >> 4;
  const int gx = gridDim.x;
  int nwg = gx * gridDim.y;
  int bid = blockIdx.y * gx + blockIdx.x;
  if ((nwg & 7) == 0) {
    int cpx = nwg >> 3;
    bid = (bid & 7) * cpx + (bid >> 3);
  }
  const int m0 = (bid / gx) * 128, n0 = (bid % gx) * 128;
  const int wm = (wid >> 1) * 64, wn = (wid & 1) * 64;
  const int sr = tid >> 2, sc = (tid & 3) * 8;
  const unsigned short* Ag = (const unsigned short*)Ab + (size_t)(m0 + sr) * K + sc;
  const unsigned short* Bg = (const unsigned short*)Bt + (size_t)(n0 + sr) * K + sc;
  f32x4 acc[4][4] = {};
  for (int k0 = 0; k0 < K; k0 += 32) {
    GLOAD_LDS16(Ag + k0, As + tid * 8);
    GLOAD_LDS16(Ag + (size_t)64 * K + k0, As + 2048 + tid * 8);
    GLOAD_LDS16(Bg + k0, Bs + tid * 8);
    GLOAD_LDS16(Bg + (size_t)64 * K + k0, Bs + 2048 + tid * 8);
    __syncthreads();
    bf16x8 af[4], bfr[4];
#pragma unroll
    for (int i = 0; i < 4; ++i) af[i] = *(const bf16x8*)&As[(wm + i * 16 + lr) * 32 + lg * 8];
#pragma unroll
    for (int i = 0; i < 4; ++i) bfr[i] = *(const bf16x8*)&Bs[(wn + i * 16 + lr) * 32 + lg * 8];
#pragma unroll
    for (int i = 0; i < 4; ++i)
#pragma unroll
      for (int jn = 0; jn < 4; ++jn)
        acc[i][jn] = __builtin_amdgcn_mfma_f32_16x16x32_bf16(af[i], bfr[jn], acc[i][jn], 0, 0, 0);
    __syncthreads();
  }
  const bool isK = KSPLIT && (n0 >= 1024) && (n0 < 2048);
#pragma unroll
  for (int i = 0; i < 4; ++i)
#pragma unroll
    for (int jn = 0; jn < 4; ++jn)
#pragma unroll
      for (int jj = 0; jj < 4; ++jj) {
        int row = m0 + wm + i * 16 + lg * 4 + jj;
        int col = n0 + wn + jn * 16 + lr;
        float v = acc[i][jn][jj] + bias[col];
        if (OUT_F32) {
          ((float*)Cp)[(size_t)row * N + col] = v;
        } else if (isK) {
          int h = (col - 1024) >> 6, d = col & 63;
          int bq = row >> 11, t = row & 2047;
          ((unsigned short*)Kbp)[(size_t)((bq * 16 + h) * 2048 + t) * 64 + d] = f2bf(v);
        } else {
          ((unsigned short*)Cp)[(size_t)row * N + col] = f2bf(v);
        }
      }
}

// ---------------- qkv(v part) -> Vt [B,H,D,T] (tiled transpose) ----------------
__global__ __launch_bounds__(256) void vtrans_kernel(const __bf16* __restrict__ qkv,
                                                     __bf16* __restrict__ Vt) {
  __shared__ __align__(16) unsigned short tile[64][72];
  int bh = blockIdx.y, b = bh >> 4, h = bh & 15;
  int t0 = blockIdx.x * 64;
  int tid = threadIdx.x;
#pragma unroll
  for (int p = 0; p < 2; ++p) {
    int idx = p * 256 + tid;
    int r = idx >> 3, c8 = (idx & 7) * 8;
    *(ushort8*)&tile[r][c8] = *(const ushort8*)((const unsigned short*)qkv +
                                                (size_t)(b * 2048 + t0 + r) * 3072 + 2048 +
                                                h * 64 + c8);
  }
  __syncthreads();
#pragma unroll
  for (int p = 0; p < 2; ++p) {
    int idx = p * 256 + tid;
    int d = idx >> 3, c8 = (idx & 7) * 8;
    ushort8 u;
#pragma unroll
    for (int i = 0; i < 8; ++i) u[i] = tile[c8 + i][d];
    *(ushort8*)((unsigned short*)Vt + (size_t)(bh * 64 + d) * 2048 + t0 + c8) = u;
  }
}

// ---------------- flash attention (causal), swapped-QK^T 32x32 ----------------
// 8 waves x 32 q-rows (QBLK=256), KVBLK=64, double-buffered LDS, 1 barrier/iter.
// No setprio (lockstep waves: m190 regime, hurts). VALU cuts: pre-scaled Q,
// diagonal-only mask, pair-tree max, defer-max, cvt_pk+permlane P repack.
__global__ __launch_bounds__(512) void attn_kernel(const __bf16* __restrict__ qkvp,
                                                   const __bf16* __restrict__ Kg,
                                                   const __bf16* __restrict__ Vt,
                                                   __bf16* __restrict__ yb) {
  __shared__ __align__(16) unsigned short Ks[2][64][72];
  __shared__ __align__(16) unsigned short Vs[2][64][72];
  const int bx = blockIdx.x;
  const int qb = 7 - (bx >> 6);  // heavy blocks first
  const int bh = bx & 63;
  const int b = bh >> 4, h = bh & 15;
  const int tid = threadIdx.x, wid = tid >> 6, lane = tid & 63;
  const int lq = lane & 31, hi = lane >> 5;
  const unsigned short* qkv = (const unsigned short*)qkvp;
  const unsigned short* Kh = (const unsigned short*)Kg + (size_t)bh * 2048 * 64;
  const unsigned short* Vh = (const unsigned short*)Vt + (size_t)bh * 64 * 2048;
  const int q0w = qb * 256 + wid * 32;
  const int jmax_w = 4 * qb + (wid >> 1);
  const int qrel = (wid & 1) * 32 + lq;
  const int J = 4 * qb + 4;
  // staging coords: 512 threads cover 64 rows x 8 x 16B
  const int r = tid >> 3, c8s = (tid & 7) * 8;

  // Q B-fragments, pre-scaled by 1/sqrt(d)*log2(e), read once from qkv
  const float qs = 0.125f * 1.44269504f;
  bf16x8 qf[4];
  {
    const unsigned short* Qg = qkv + (size_t)(b * 2048 + q0w + lq) * 3072 + h * 64;
#pragma unroll
    for (int dc = 0; dc < 4; ++dc) {
      ushort8 uq = *(const ushort8*)(Qg + dc * 16 + hi * 8);
      uint4v w;
#pragma unroll
      for (int i = 0; i < 4; ++i) {
        float lo = bf2f(uq[2 * i]) * qs;
        float hh = bf2f(uq[2 * i + 1]) * qs;
        unsigned int up;
        asm("v_cvt_pk_bf16_f32 %0, %1, %2" : "=v"(up) : "v"(lo), "v"(hh));
        w[i] = up;
      }
      qf[dc] = __builtin_bit_cast(bf16x8, w);
    }
  }

  f32x16 yacc[2] = {};
  float m_r = -1e30f, l_r = 0.f;

  // prologue: stage tile 0 into buffer 0
  *(ushort8*)&Ks[0][r][c8s] = *(const ushort8*)(Kh + (size_t)r * 64 + c8s);
  *(ushort8*)&Vs[0][r][c8s] = *(const ushort8*)(Vh + (size_t)r * 2048 + c8s);

  for (int j = 0; j < J; ++j) {
    __syncthreads();  // buf (j&1) holds tile j; prior reads of other buf done
    if (j + 1 < J) {  // stage next tile; compiler overlaps loads with compute below
      int bi = (j + 1) & 1;
      *(ushort8*)&Ks[bi][r][c8s] =
          *(const ushort8*)(Kh + (size_t)((j + 1) * 64 + r) * 64 + c8s);
      *(ushort8*)&Vs[bi][r][c8s] =
          *(const ushort8*)(Vh + (size_t)r * 2048 + (j + 1) * 64 + c8s);
    }
    if (j <= jmax_w) {
      const int cb = j & 1;
      // --- S^T = K @ Q^T (Q pre-scaled)
      f32x16 sa[2];
#pragma unroll
      for (int kt32 = 0; kt32 < 2; ++kt32) {
        f32x16 s = {};
#pragma unroll
        for (int dc = 0; dc < 4; ++dc) {
          bf16x8 kf = *(const bf16x8*)&Ks[cb][kt32 * 32 + lq][dc * 16 + hi * 8];
          s = __builtin_amdgcn_mfma_f32_32x32x16_bf16(kf, qf[dc], s, 0, 0, 0);
        }
        sa[kt32] = s;
      }
      // --- causal mask (diagonal tile only, wave-uniform branch)
      if (j == jmax_w) {
#pragma unroll
        for (int kt32 = 0; kt32 < 2; ++kt32)
#pragma unroll
          for (int reg = 0; reg < 16; ++reg) {
            int kl = kt32 * 32 + (reg & 3) + 8 * (reg >> 2) + 4 * hi;
            if (kl > qrel) sa[kt32][reg] = -1e30f;
          }
      }
      // --- row max (pair tree), defer-max
      float pmax = -1e30f;
#pragma unroll
      for (int kt32 = 0; kt32 < 2; ++kt32)
#pragma unroll
        for (int reg = 0; reg < 16; reg += 4)
          pmax = fmaxf(pmax, fmaxf(fmaxf(sa[kt32][reg], sa[kt32][reg + 1]),
                                   fmaxf(sa[kt32][reg + 2], sa[kt32][reg + 3])));
      pmax = fmaxf(pmax, __shfl_xor(pmax, 32));
      const bool need = __any(pmax > m_r + 8.f) != 0;
      const float mnew = need ? fmaxf(m_r, pmax) : m_r;
      const float alpha = exp2f(m_r - mnew);
      // --- exp + row sum + pack to bf16 pairs
      unsigned int u[2][8];
      float rs = 0.f;
#pragma unroll
      for (int kt32 = 0; kt32 < 2; ++kt32)
#pragma unroll
        for (int rr = 0; rr < 8; ++rr) {
          float p0 = exp2f(sa[kt32][2 * rr] - mnew);
          float p1 = exp2f(sa[kt32][2 * rr + 1] - mnew);
          rs += p0 + p1;
          unsigned int up;
          asm("v_cvt_pk_bf16_f32 %0, %1, %2" : "=v"(up) : "v"(p0), "v"(p1));
          u[kt32][rr] = up;
        }
      rs += __shfl_xor(rs, 32);
      l_r = l_r * alpha + rs;
      m_r = mnew;
      if (need) {
#pragma unroll
        for (int reg = 0; reg < 16; ++reg) {
          int row = (reg & 3) + 8 * (reg >> 2) + 4 * hi;
          float ac = __shfl(alpha, row);
          yacc[0][reg] *= ac;
          yacc[1][reg] *= ac;
        }
      }
      // --- PV: repack P via permlane32_swap, accumulate Y
#pragma unroll
      for (int kt = 0; kt < 4; ++kt) {
        const int kt32 = kt >> 1, off = 4 * (kt & 1);
        unsigned int a0 = u[kt32][off + 0], a2 = u[kt32][off + 2];
        unsigned int a1 = u[kt32][off + 1], a3 = u[kt32][off + 3];
        asm("v_permlane32_swap_b32 %0, %1" : "+v"(a0), "+v"(a2));
        asm("v_permlane32_swap_b32 %0, %1" : "+v"(a1), "+v"(a3));
        uint4v pav = {a0, a1, a2, a3};
        bf16x8 paf = __builtin_bit_cast(bf16x8, pav);
#pragma unroll
        for (int dt = 0; dt < 2; ++dt) {
          bf16x8 vf = *(const bf16x8*)&Vs[cb][dt * 32 + lq][kt * 16 + hi * 8];
          yacc[dt] = __builtin_amdgcn_mfma_f32_32x32x16_bf16(paf, vf, yacc[dt], 0, 0, 0);
        }
      }
    }
  }
  // --- epilogue
#pragma unroll
  for (int reg = 0; reg < 16; ++reg) {
    int row = (reg & 3) + 8 * (reg >> 2) + 4 * hi;
    float linv = 1.f / __shfl(l_r, row);
    int qg = q0w + row;
#pragma unroll
    for (int dt = 0; dt < 2; ++dt) {
      float v = yacc[dt][reg] * linv;
      ((unsigned short*)yb)[(size_t)(b * 2048 + qg) * 1024 + h * 64 + dt * 32 + lq] = f2bf(v);
    }
  }
}

extern "C" void kernel_launch(void* const* d_in, const int* in_sizes, int n_in,
                              void* d_out, int out_size, void* d_ws, size_t ws_size,
                              hipStream_t stream) {
  const float* x = (const float*)d_in[0];
  const float* W_attn = (const float*)d_in[1];
  const float* b_attn = (const float*)d_in[2];
  const float* W_proj = (const float*)d_in[3];
  const float* b_proj = (const float*)d_in[4];
  float* out = (float*)d_out;
  char* ws = (char*)d_ws;

  size_t off = 0;
  __bf16* WtA = (__bf16*)(ws + off); off += (size_t)3072 * 1024 * 2;
  __bf16* WtP = (__bf16*)(ws + off); off += (size_t)1024 * 1024 * 2;
  __bf16* qkv = (__bf16*)(ws + off); off += (size_t)8192 * 3072 * 2;
  __bf16* Kb  = (__bf16*)(ws + off); off += (size_t)64 * 2048 * 64 * 2;
  __bf16* Vtb = (__bf16*)(ws + off); off += (size_t)64 * 2048 * 64 * 2;
  // xb (x in bf16) is dead after GEMM1; yb written only after attn -> alias
  __bf16* xyb = (__bf16*)(ws + off); off += (size_t)8192 * 1024 * 2;
  __bf16* xb = xyb;
  __bf16* yb = xyb;
  (void)ws_size; (void)in_sizes; (void)n_in; (void)out_size;

  f32_to_bf16_kernel<<<4096, 256, 0, stream>>>(x, xb);
  wtrans_kernel<<<dim3(3072 / 32, 1024 / 32), dim3(32, 8), 0, stream>>>(W_attn, WtA, 1024, 3072);
  wtrans_kernel<<<dim3(1024 / 32, 1024 / 32), dim3(32, 8), 0, stream>>>(W_proj, WtP, 1024, 1024);
  // qkv GEMM; k columns redirected to Kb (fused reshape_k)
  gemm_bt_kernel<0, 1><<<dim3(24, 64), 256, 0, stream>>>(xb, WtA, b_attn, qkv, Kb, 8192, 3072, 1024);
  vtrans_kernel<<<dim3(32, 64), 256, 0, stream>>>(qkv, Vtb);
  attn_kernel<<<dim3(512), 512, 0, stream>>>(qkv, Kb, Vtb, yb);
  gemm_bt_kernel<1, 0><<<dim3(8, 64), 256, 0, stream>>>(yb, WtP, b_proj, out, nullptr, 8192, 1024, 1024);
}

// Round 7
// 192.164 us; speedup vs baseline: 1.0924x; 1.0512x over previous
//
#include <hip/hip_runtime.h>

typedef __bf16 bf16x8 __attribute__((ext_vector_type(8)));
typedef float f32x4 __attribute__((ext_vector_type(4)));
typedef float f32x16 __attribute__((ext_vector_type(16)));
typedef unsigned short ushort8 __attribute__((ext_vector_type(8)));
typedef unsigned int uint4v __attribute__((ext_vector_type(4)));

__device__ __forceinline__ unsigned short f2bf(float f) {
  __bf16 b = (__bf16)f;
  return __builtin_bit_cast(unsigned short, b);
}
__device__ __forceinline__ float bf2f(unsigned short u) {
  unsigned int x = ((unsigned int)u) << 16;
  return __builtin_bit_cast(float, x);
}

// async global->LDS, 16B per lane; LDS dest must be wave-uniform base + lane*16
#define GLOAD_LDS16(g, l)                                              \
  __builtin_amdgcn_global_load_lds(                                    \
      (const __attribute__((address_space(1))) void*)(g),              \
      (__attribute__((address_space(3))) void*)(l), 16, 0, 0)

// ---------------- x f32 -> bf16 ----------------
__global__ __launch_bounds__(256) void f32_to_bf16_kernel(const float* __restrict__ in,
                                                          __bf16* __restrict__ out) {
  int i = blockIdx.x * 256 + threadIdx.x;
  const float4* p = (const float4*)(in + (size_t)i * 8);
  float4 f0 = p[0], f1 = p[1];
  ushort8 u = {f2bf(f0.x), f2bf(f0.y), f2bf(f0.z), f2bf(f0.w),
               f2bf(f1.x), f2bf(f1.y), f2bf(f1.z), f2bf(f1.w)};
  *(ushort8*)((unsigned short*)out + (size_t)i * 8) = u;
}

// ---------------- W transpose + f32->bf16 convert: Wt[n][k] = W[k][n] ----------------
__global__ __launch_bounds__(256) void wtrans_kernel(const float* __restrict__ W,
                                                     __bf16* __restrict__ Wt,
                                                     int K, int N) {
  __shared__ float tile[32][33];
  int tx = threadIdx.x, ty = threadIdx.y;  // block (32,8)
  int n0 = blockIdx.x * 32, k0 = blockIdx.y * 32;
#pragma unroll
  for (int i = 0; i < 32; i += 8)
    tile[ty + i][tx] = W[(size_t)(k0 + ty + i) * N + n0 + tx];
  __syncthreads();
#pragma unroll
  for (int i = 0; i < 32; i += 8)
    Wt[(size_t)(n0 + ty + i) * K + k0 + tx] = (__bf16)tile[tx][ty + i];
}

// ---------------- GEMM 256x128x64, counted-vmcnt pipeline (T2+T4+T5) ----------------
// C[M,N] = A[M,K] @ Bt[N,K]^T + bias. 512 thr = 8 waves (4 M x 2 N), 64x64/wave.
// LDS: dbuf A[256][64] + B[128][64] = 96 KB -> 1 block/CU, 2 waves/SIMD.
// Staging: 6 global_load_lds_dwordx4 per K-step; s_waitcnt vmcnt(6) (counted,
// never 0 mid-loop); raw s_barrier (asm, no implicit vmcnt(0) drain).
// T2 swizzle: LDS slot p of row r holds logical slot p^(r&7); source pre-swizzled,
// ds_read XOR'd (involution, both sides).
// KSPLIT=1: column-blocks in [1024,2048) (K part of qkv) redirect to Kb[B,H,T,D].
template <int OUT_F32, int KSPLIT>
__global__ __launch_bounds__(512, 2) void gemm256_kernel(const __bf16* __restrict__ Ab,
                                                         const __bf16* __restrict__ Bt,
                                                         const float* __restrict__ bias,
                                                         void* __restrict__ Cp,
                                                         __bf16* __restrict__ Kbp,
                                                         int M, int N, int K) {
  __shared__ __align__(16) unsigned short As[2][256 * 64];
  __shared__ __align__(16) unsigned short Bs[2][128 * 64];
  const int tid = threadIdx.x;
  const int lane = tid & 63;
  const int wid = tid >> 6;
  const int lr = lane & 15, lg = lane >> 4;
  const int wr = wid >> 1, wc = wid & 1;  // 4 x 2 waves
  const int gx = gridDim.x;
  int nwg = gx * gridDim.y;
  int bid = blockIdx.y * gx + blockIdx.x;
  if ((nwg & 7) == 0) {  // XCD swizzle (bijective: nwg % 8 == 0)
    int cpx = nwg >> 3;
    bid = (bid & 7) * cpx + (bid >> 3);
  }
  const int m0 = (bid / gx) * 256, n0 = (bid % gx) * 128;
  // staging coords: 512 threads cover 64 rows x 8 slots of 16B per issue
  const int srow = tid >> 3;                          // 0..63
  const int scol = ((tid & 7) ^ (srow & 7)) * 8;      // pre-swizzled source col
  const unsigned short* Ag = (const unsigned short*)Ab + (size_t)(m0 + srow) * K + scol;
  const unsigned short* Bg = (const unsigned short*)Bt + (size_t)(n0 + srow) * K + scol;

#define STAGE256(t, bi)                                                      \
  {                                                                          \
    const int _k0 = (t) * 64;                                                \
    GLOAD_LDS16(Ag + _k0, &As[bi][tid * 8]);                                 \
    GLOAD_LDS16(Ag + (size_t)64 * K + _k0, &As[bi][4096 + tid * 8]);         \
    GLOAD_LDS16(Ag + (size_t)128 * K + _k0, &As[bi][8192 + tid * 8]);        \
    GLOAD_LDS16(Ag + (size_t)192 * K + _k0, &As[bi][12288 + tid * 8]);       \
    GLOAD_LDS16(Bg + _k0, &Bs[bi][tid * 8]);                                 \
    GLOAD_LDS16(Bg + (size_t)64 * K + _k0, &Bs[bi][4096 + tid * 8]);         \
  }

  f32x4 acc[4][4] = {};
  const int nst = K >> 6;
  STAGE256(0, 0);
  STAGE256(1, 1);
  // per-thread read offsets (swizzled): row&7 == lr&7 for all our rows
  int aoff[4][2], boff[4][2];
#pragma unroll
  for (int t = 0; t < 4; ++t)
#pragma unroll
    for (int ks = 0; ks < 2; ++ks) {
      int slot = ((ks * 4 + lg) ^ (lr & 7));
      aoff[t][ks] = (wr * 64 + t * 16 + lr) * 64 + slot * 8;
      boff[t][ks] = (wc * 64 + t * 16 + lr) * 64 + slot * 8;
    }

  for (int i = 0; i < nst; ++i) {
    const int cur = i & 1;
    if (i + 1 < nst)
      asm volatile("s_waitcnt vmcnt(6)" ::: "memory");
    else
      asm volatile("s_waitcnt vmcnt(0)" ::: "memory");
    asm volatile("s_barrier" ::: "memory");  // B1: tile i visible in buf[cur]
    bf16x8 af[4][2], bq[4][2];
#pragma unroll
    for (int t = 0; t < 4; ++t)
#pragma unroll
      for (int ks = 0; ks < 2; ++ks) {
        af[t][ks] = *(const bf16x8*)&As[cur][aoff[t][ks]];
        bq[t][ks] = *(const bf16x8*)&Bs[cur][boff[t][ks]];
      }
    asm volatile("s_waitcnt lgkmcnt(0)" ::: "memory");  // frags in regs
    asm volatile("s_barrier" ::: "memory");  // B2: all waves done reading buf[cur]
    if (i + 2 < nst) STAGE256(i + 2, cur);   // restage freed buffer (6 loads in flight)
    __builtin_amdgcn_s_setprio(1);
#pragma unroll
    for (int mt = 0; mt < 4; ++mt)
#pragma unroll
      for (int nt = 0; nt < 4; ++nt)
#pragma unroll
        for (int ks = 0; ks < 2; ++ks)
          acc[mt][nt] =
              __builtin_amdgcn_mfma_f32_16x16x32_bf16(af[mt][ks], bq[nt][ks], acc[mt][nt], 0, 0, 0);
    __builtin_amdgcn_s_setprio(0);
  }
#undef STAGE256

  const bool isK = KSPLIT && (n0 >= 1024) && (n0 < 2048);
#pragma unroll
  for (int mt = 0; mt < 4; ++mt)
#pragma unroll
    for (int nt = 0; nt < 4; ++nt)
#pragma unroll
      for (int jj = 0; jj < 4; ++jj) {
        int row = m0 + wr * 64 + mt * 16 + lg * 4 + jj;
        int col = n0 + wc * 64 + nt * 16 + lr;
        float v = acc[mt][nt][jj] + bias[col];
        if (OUT_F32) {
          ((float*)Cp)[(size_t)row * N + col] = v;
        } else if (isK) {
          int h = (col - 1024) >> 6, d = col & 63;
          int bq2 = row >> 11, t = row & 2047;
          ((unsigned short*)Kbp)[(size_t)((bq2 * 16 + h) * 2048 + t) * 64 + d] = f2bf(v);
        } else {
          ((unsigned short*)Cp)[(size_t)row * N + col] = f2bf(v);
        }
      }
}

// ---------------- qkv(v part) -> Vt [B,H,D,T] (tiled transpose) ----------------
__global__ __launch_bounds__(256) void vtrans_kernel(const __bf16* __restrict__ qkv,
                                                     __bf16* __restrict__ Vt) {
  __shared__ __align__(16) unsigned short tile[64][72];
  int bh = blockIdx.y, b = bh >> 4, h = bh & 15;
  int t0 = blockIdx.x * 64;
  int tid = threadIdx.x;
#pragma unroll
  for (int p = 0; p < 2; ++p) {
    int idx = p * 256 + tid;
    int r = idx >> 3, c8 = (idx & 7) * 8;
    *(ushort8*)&tile[r][c8] = *(const ushort8*)((const unsigned short*)qkv +
                                                (size_t)(b * 2048 + t0 + r) * 3072 + 2048 +
                                                h * 64 + c8);
  }
  __syncthreads();
#pragma unroll
  for (int p = 0; p < 2; ++p) {
    int idx = p * 256 + tid;
    int d = idx >> 3, c8 = (idx & 7) * 8;
    ushort8 u;
#pragma unroll
    for (int i = 0; i < 8; ++i) u[i] = tile[c8 + i][d];
    *(ushort8*)((unsigned short*)Vt + (size_t)(bh * 64 + d) * 2048 + t0 + c8) = u;
  }
}

// ---------------- flash attention (causal), swapped-QK^T 32x32 ----------------
// 8 waves x 32 q-rows (QBLK=256), KVBLK=64, double-buffered LDS, 1 barrier/iter.
__global__ __launch_bounds__(512) void attn_kernel(const __bf16* __restrict__ qkvp,
                                                   const __bf16* __restrict__ Kg,
                                                   const __bf16* __restrict__ Vt,
                                                   __bf16* __restrict__ yb) {
  __shared__ __align__(16) unsigned short Ks[2][64][72];
  __shared__ __align__(16) unsigned short Vs[2][64][72];
  const int bx = blockIdx.x;
  const int qb = 7 - (bx >> 6);  // heavy blocks first
  const int bh = bx & 63;
  const int b = bh >> 4, h = bh & 15;
  const int tid = threadIdx.x, wid = tid >> 6, lane = tid & 63;
  const int lq = lane & 31, hi = lane >> 5;
  const unsigned short* qkv = (const unsigned short*)qkvp;
  const unsigned short* Kh = (const unsigned short*)Kg + (size_t)bh * 2048 * 64;
  const unsigned short* Vh = (const unsigned short*)Vt + (size_t)bh * 64 * 2048;
  const int q0w = qb * 256 + wid * 32;
  const int jmax_w = 4 * qb + (wid >> 1);
  const int qrel = (wid & 1) * 32 + lq;
  const int J = 4 * qb + 4;
  const int r = tid >> 3, c8s = (tid & 7) * 8;

  const float qs = 0.125f * 1.44269504f;
  bf16x8 qf[4];
  {
    const unsigned short* Qg = qkv + (size_t)(b * 2048 + q0w + lq) * 3072 + h * 64;
#pragma unroll
    for (int dc = 0; dc < 4; ++dc) {
      ushort8 uq = *(const ushort8*)(Qg + dc * 16 + hi * 8);
      uint4v w;
#pragma unroll
      for (int i = 0; i < 4; ++i) {
        float lo = bf2f(uq[2 * i]) * qs;
        float hh = bf2f(uq[2 * i + 1]) * qs;
        unsigned int up;
        asm("v_cvt_pk_bf16_f32 %0, %1, %2" : "=v"(up) : "v"(lo), "v"(hh));
        w[i] = up;
      }
      qf[dc] = __builtin_bit_cast(bf16x8, w);
    }
  }

  f32x16 yacc[2] = {};
  float m_r = -1e30f, l_r = 0.f;

  *(ushort8*)&Ks[0][r][c8s] = *(const ushort8*)(Kh + (size_t)r * 64 + c8s);
  *(ushort8*)&Vs[0][r][c8s] = *(const ushort8*)(Vh + (size_t)r * 2048 + c8s);

  for (int j = 0; j < J; ++j) {
    __syncthreads();
    if (j + 1 < J) {
      int bi = (j + 1) & 1;
      *(ushort8*)&Ks[bi][r][c8s] =
          *(const ushort8*)(Kh + (size_t)((j + 1) * 64 + r) * 64 + c8s);
      *(ushort8*)&Vs[bi][r][c8s] =
          *(const ushort8*)(Vh + (size_t)r * 2048 + (j + 1) * 64 + c8s);
    }
    if (j <= jmax_w) {
      const int cb = j & 1;
      f32x16 sa[2];
#pragma unroll
      for (int kt32 = 0; kt32 < 2; ++kt32) {
        f32x16 s = {};
#pragma unroll
        for (int dc = 0; dc < 4; ++dc) {
          bf16x8 kf = *(const bf16x8*)&Ks[cb][kt32 * 32 + lq][dc * 16 + hi * 8];
          s = __builtin_amdgcn_mfma_f32_32x32x16_bf16(kf, qf[dc], s, 0, 0, 0);
        }
        sa[kt32] = s;
      }
      if (j == jmax_w) {
#pragma unroll
        for (int kt32 = 0; kt32 < 2; ++kt32)
#pragma unroll
          for (int reg = 0; reg < 16; ++reg) {
            int kl = kt32 * 32 + (reg & 3) + 8 * (reg >> 2) + 4 * hi;
            if (kl > qrel) sa[kt32][reg] = -1e30f;
          }
      }
      float pmax = -1e30f;
#pragma unroll
      for (int kt32 = 0; kt32 < 2; ++kt32)
#pragma unroll
        for (int reg = 0; reg < 16; reg += 4)
          pmax = fmaxf(pmax, fmaxf(fmaxf(sa[kt32][reg], sa[kt32][reg + 1]),
                                   fmaxf(sa[kt32][reg + 2], sa[kt32][reg + 3])));
      pmax = fmaxf(pmax, __shfl_xor(pmax, 32));
      const bool need = __any(pmax > m_r + 8.f) != 0;
      const float mnew = need ? fmaxf(m_r, pmax) : m_r;
      const float alpha = exp2f(m_r - mnew);
      unsigned int u[2][8];
      float rs = 0.f;
#pragma unroll
      for (int kt32 = 0; kt32 < 2; ++kt32)
#pragma unroll
        for (int rr = 0; rr < 8; ++rr) {
          float p0 = exp2f(sa[kt32][2 * rr] - mnew);
          float p1 = exp2f(sa[kt32][2 * rr + 1] - mnew);
          rs += p0 + p1;
          unsigned int up;
          asm("v_cvt_pk_bf16_f32 %0, %1, %2" : "=v"(up) : "v"(p0), "v"(p1));
          u[kt32][rr] = up;
        }
      rs += __shfl_xor(rs, 32);
      l_r = l_r * alpha + rs;
      m_r = mnew;
      if (need) {
#pragma unroll
        for (int reg = 0; reg < 16; ++reg) {
          int row = (reg & 3) + 8 * (reg >> 2) + 4 * hi;
          float ac = __shfl(alpha, row);
          yacc[0][reg] *= ac;
          yacc[1][reg] *= ac;
        }
      }
#pragma unroll
      for (int kt = 0; kt < 4; ++kt) {
        const int kt32 = kt >> 1, off = 4 * (kt & 1);
        unsigned int a0 = u[kt32][off + 0], a2 = u[kt32][off + 2];
        unsigned int a1 = u[kt32][off + 1], a3 = u[kt32][off + 3];
        asm("v_permlane32_swap_b32 %0, %1" : "+v"(a0), "+v"(a2));
        asm("v_permlane32_swap_b32 %0, %1" : "+v"(a1), "+v"(a3));
        uint4v pav = {a0, a1, a2, a3};
        bf16x8 paf = __builtin_bit_cast(bf16x8, pav);
#pragma unroll
        for (int dt = 0; dt < 2; ++dt) {
          bf16x8 vf = *(const bf16x8*)&Vs[cb][dt * 32 + lq][kt * 16 + hi * 8];
          yacc[dt] = __builtin_amdgcn_mfma_f32_32x32x16_bf16(paf, vf, yacc[dt], 0, 0, 0);
        }
      }
    }
  }
#pragma unroll
  for (int reg = 0; reg < 16; ++reg) {
    int row = (reg & 3) + 8 * (reg >> 2) + 4 * hi;
    float linv = 1.f / __shfl(l_r, row);
    int qg = q0w + row;
#pragma unroll
    for (int dt = 0; dt < 2; ++dt) {
      float v = yacc[dt][reg] * linv;
      ((unsigned short*)yb)[(size_t)(b * 2048 + qg) * 1024 + h * 64 + dt * 32 + lq] = f2bf(v);
    }
  }
}

extern "C" void kernel_launch(void* const* d_in, const int* in_sizes, int n_in,
                              void* d_out, int out_size, void* d_ws, size_t ws_size,
                              hipStream_t stream) {
  const float* x = (const float*)d_in[0];
  const float* W_attn = (const float*)d_in[1];
  const float* b_attn = (const float*)d_in[2];
  const float* W_proj = (const float*)d_in[3];
  const float* b_proj = (const float*)d_in[4];
  float* out = (float*)d_out;
  char* ws = (char*)d_ws;

  size_t off = 0;
  __bf16* WtA = (__bf16*)(ws + off); off += (size_t)3072 * 1024 * 2;
  __bf16* WtP = (__bf16*)(ws + off); off += (size_t)1024 * 1024 * 2;
  __bf16* qkv = (__bf16*)(ws + off); off += (size_t)8192 * 3072 * 2;
  __bf16* Kb  = (__bf16*)(ws + off); off += (size_t)64 * 2048 * 64 * 2;
  __bf16* Vtb = (__bf16*)(ws + off); off += (size_t)64 * 2048 * 64 * 2;
  // xb (x in bf16) dead after GEMM1; yb written only after attn -> alias
  __bf16* xyb = (__bf16*)(ws + off); off += (size_t)8192 * 1024 * 2;
  __bf16* xb = xyb;
  __bf16* yb = xyb;
  (void)ws_size; (void)in_sizes; (void)n_in; (void)out_size;

  f32_to_bf16_kernel<<<4096, 256, 0, stream>>>(x, xb);
  wtrans_kernel<<<dim3(3072 / 32, 1024 / 32), dim3(32, 8), 0, stream>>>(W_attn, WtA, 1024, 3072);
  wtrans_kernel<<<dim3(1024 / 32, 1024 / 32), dim3(32, 8), 0, stream>>>(W_proj, WtP, 1024, 1024);
  // qkv GEMM (256x128 counted-vmcnt); k columns redirected to Kb
  gemm256_kernel<0, 1><<<dim3(24, 32), 512, 0, stream>>>(xb, WtA, b_attn, qkv, Kb, 8192, 3072, 1024);
  vtrans_kernel<<<dim3(32, 64), 256, 0, stream>>>(qkv, Vtb);
  attn_kernel<<<dim3(512), 512, 0, stream>>>(qkv, Kb, Vtb, yb);
  // proj GEMM: 8x32 = 256 blocks = exactly 1/CU
  gemm256_kernel<1, 0><<<dim3(8, 32), 512, 0, stream>>>(yb, WtP, b_proj, out, nullptr, 8192, 1024, 1024);
}